// Round 11
// baseline (91.308 us; speedup 1.0000x reference)
//
#include <hip/hip_runtime.h>
#include <math.h>

// Round 10: even/odd spectral split -> two 4096-point FFTs (8^4, no radix-2).
//   Z[2m]   = FFT4096(z)[m];  Z[2m+1] = FFT4096(z * e^{-2pi i j/8192})[m]
//   o[n]    = IFr4096(Q'e)[n] + e^{+2pi i n/8192} * IFr4096(Q'o)[n]
//   T-side: Te = FFT4096(t_j + t_{j+4096}); To = FFT4096((t_j - t_{j+4096})*mod)
// Wave-local stages: with 512 butterflies/buffer and wave-aligned p, the
// q=64->q=8->q=1 transitions stay within one 64-lane wave (same-wave DS ops
// execute in order) -> no barrier, only a compiler fence. Barriers 11 -> 6.
// conv: 512 blocks x 1024 thr, 4 padded 4096-buffers = 139264 B, float4 I/O.
// tsep: 256 blocks x 1024 thr, 2 buffers (Te,To), same structure.

#define TWO_PI 6.28318530717958647692f
#define RSQRT2 0.70710678118654752440f
#define PADL(i) ((i) + ((i) >> 4))
#define BUF_ELEMS (4096 + 256)            // 4352 float2 = 34816 B per buffer
#define WFENCE() asm volatile("" ::: "memory")

__device__ __forceinline__ float2 cadd(float2 a, float2 b){ return make_float2(a.x+b.x, a.y+b.y); }
__device__ __forceinline__ float2 csub(float2 a, float2 b){ return make_float2(a.x-b.x, a.y-b.y); }
__device__ __forceinline__ float2 cmul(float2 a, float2 b){ return make_float2(a.x*b.x - a.y*b.y, a.x*b.y + a.y*b.x); }
__device__ __forceinline__ float2 mulnegi(float2 a){ return make_float2(a.y, -a.x); }
__device__ __forceinline__ float2 mulposi(float2 a){ return make_float2(-a.y, a.x); }
__device__ __forceinline__ float2 mulw81(float2 z){ return make_float2(RSQRT2*(z.x+z.y), RSQRT2*(z.y-z.x)); }  // e^{-i pi/4}
__device__ __forceinline__ float2 mulw83(float2 z){ return make_float2(RSQRT2*(z.y-z.x), -RSQRT2*(z.x+z.y)); } // e^{-i 3pi/4}
__device__ __forceinline__ float2 mulv81(float2 z){ return make_float2(RSQRT2*(z.x-z.y), RSQRT2*(z.x+z.y)); }  // e^{+i pi/4}
__device__ __forceinline__ float2 mulv83(float2 z){ return make_float2(-RSQRT2*(z.x+z.y), RSQRT2*(z.x-z.y)); } // e^{+i 3pi/4}

__device__ __forceinline__ int rev8_12(int u) {   // 4-octal-digit reversal of 12 bits
    return ((u & 7) << 9) | (((u >> 3) & 7) << 6) | (((u >> 6) & 7) << 3) | ((u >> 9) & 7);
}

__device__ __forceinline__ void dft8_fwd(float2& a0, float2& a1, float2& a2, float2& a3,
                                         float2& a4, float2& a5, float2& a6, float2& a7) {
    float2 s02 = cadd(a0,a4), d02 = csub(a0,a4), s13 = cadd(a2,a6), d13 = csub(a2,a6);
    float2 E0 = cadd(s02,s13), E2 = csub(s02,s13);
    float2 E1 = cadd(d02, mulnegi(d13)), E3 = csub(d02, mulnegi(d13));
    float2 t02 = cadd(a1,a5), u02 = csub(a1,a5), t13 = cadd(a3,a7), u13 = csub(a3,a7);
    float2 O0 = cadd(t02,t13), O2 = csub(t02,t13);
    float2 O1 = cadd(u02, mulnegi(u13)), O3 = csub(u02, mulnegi(u13));
    float2 W1 = mulw81(O1), W2 = mulnegi(O2), W3 = mulw83(O3);
    a0 = cadd(E0,O0); a4 = csub(E0,O0);
    a1 = cadd(E1,W1); a5 = csub(E1,W1);
    a2 = cadd(E2,W2); a6 = csub(E2,W2);
    a3 = cadd(E3,W3); a7 = csub(E3,W3);
}

__device__ __forceinline__ void dft8_inv(float2& a0, float2& a1, float2& a2, float2& a3,
                                         float2& a4, float2& a5, float2& a6, float2& a7) {
    float2 s02 = cadd(a0,a4), d02 = csub(a0,a4), s13 = cadd(a2,a6), d13 = csub(a2,a6);
    float2 P0 = cadd(s02,s13), P2 = csub(s02,s13);
    float2 P1 = cadd(d02, mulposi(d13)), P3 = csub(d02, mulposi(d13));
    float2 t02 = cadd(a1,a5), u02 = csub(a1,a5), t13 = cadd(a3,a7), u13 = csub(a3,a7);
    float2 Q0 = cadd(t02,t13), Q2 = csub(t02,t13);
    float2 Q1 = cadd(u02, mulposi(u13)), Q3 = csub(u02, mulposi(u13));
    float2 W1 = mulv81(Q1), W2 = mulposi(Q2), W3 = mulv83(Q3);
    a0 = cadd(P0,Q0); a4 = csub(P0,Q0);
    a1 = cadd(P1,W1); a5 = csub(P1,W1);
    a2 = cadd(P2,W2); a6 = csub(P2,W2);
    a3 = cadd(P3,W3); a7 = csub(P3,W3);
}

__device__ __forceinline__ void fwd_one(float2* __restrict__ S,
    int i0,int i1,int i2,int i3,int i4,int i5,int i6,int i7,
    float2 w1,float2 w2,float2 w3,float2 w4,float2 w5,float2 w6,float2 w7) {
    float2 a0=S[i0],a1=S[i1],a2=S[i2],a3=S[i3],a4=S[i4],a5=S[i5],a6=S[i6],a7=S[i7];
    dft8_fwd(a0,a1,a2,a3,a4,a5,a6,a7);
    S[i0]=a0;           S[i1]=cmul(a1,w1); S[i2]=cmul(a2,w2); S[i3]=cmul(a3,w3);
    S[i4]=cmul(a4,w4);  S[i5]=cmul(a5,w5); S[i6]=cmul(a6,w6); S[i7]=cmul(a7,w7);
}

__device__ __forceinline__ void inv_one(float2* __restrict__ S,
    int i0,int i1,int i2,int i3,int i4,int i5,int i6,int i7,
    float2 w1,float2 w2,float2 w3,float2 w4,float2 w5,float2 w6,float2 w7) {
    float2 a0=S[i0];
    float2 a1=cmul(S[i1],w1), a2=cmul(S[i2],w2), a3=cmul(S[i3],w3), a4=cmul(S[i4],w4),
           a5=cmul(S[i5],w5), a6=cmul(S[i6],w6), a7=cmul(S[i7],w7);
    dft8_inv(a0,a1,a2,a3,a4,a5,a6,a7);
    S[i0]=a0; S[i1]=a1; S[i2]=a2; S[i3]=a3; S[i4]=a4; S[i5]=a5; S[i6]=a6; S[i7]=a7;
}

__device__ __forceinline__ void plain_one_fwd(float2* __restrict__ S, int p) {   // q=1, no twiddles
    const int base = p << 3;
    const int i0=PADL(base),i1=PADL(base+1),i2=PADL(base+2),i3=PADL(base+3),
              i4=PADL(base+4),i5=PADL(base+5),i6=PADL(base+6),i7=PADL(base+7);
    float2 a0=S[i0],a1=S[i1],a2=S[i2],a3=S[i3],a4=S[i4],a5=S[i5],a6=S[i6],a7=S[i7];
    dft8_fwd(a0,a1,a2,a3,a4,a5,a6,a7);
    S[i0]=a0; S[i1]=a1; S[i2]=a2; S[i3]=a3; S[i4]=a4; S[i5]=a5; S[i6]=a6; S[i7]=a7;
}

__device__ __forceinline__ void plain_one_inv(float2* __restrict__ S, int p) {
    const int base = p << 3;
    const int i0=PADL(base),i1=PADL(base+1),i2=PADL(base+2),i3=PADL(base+3),
              i4=PADL(base+4),i5=PADL(base+5),i6=PADL(base+6),i7=PADL(base+7);
    float2 a0=S[i0],a1=S[i1],a2=S[i2],a3=S[i3],a4=S[i4],a5=S[i5],a6=S[i6],a7=S[i7];
    dft8_inv(a0,a1,a2,a3,a4,a5,a6,a7);
    S[i0]=a0; S[i1]=a1; S[i2]=a2; S[i3]=a3; S[i4]=a4; S[i5]=a5; S[i6]=a6; S[i7]=a7;
}

#define WCHAIN(w1, w2,w3,w4,w5,w6,w7) \
    float2 w2 = cmul(w1,w1), w3 = cmul(w2,w1), w4 = cmul(w2,w2), \
           w5 = cmul(w4,w1), w6 = cmul(w4,w2), w7 = cmul(w4,w3)

template<int LQ>
__device__ __forceinline__ void fwd_pair(float2* __restrict__ Sa, float2* __restrict__ Sb, int p) {
    const int q = 1 << LQ;
    const int m = p & (q - 1);
    const int B = ((p >> LQ) << (LQ + 3)) + m;
    const int i0=PADL(B),i1=PADL(B+q),i2=PADL(B+2*q),i3=PADL(B+3*q),
              i4=PADL(B+4*q),i5=PADL(B+5*q),i6=PADL(B+6*q),i7=PADL(B+7*q);
    float sn, cs;
    __sincosf(-TWO_PI * (float)m / (float)(q << 3), &sn, &cs);
    float2 w1 = make_float2(cs, sn);
    WCHAIN(w1, w2,w3,w4,w5,w6,w7);
    fwd_one(Sa,i0,i1,i2,i3,i4,i5,i6,i7,w1,w2,w3,w4,w5,w6,w7);
    fwd_one(Sb,i0,i1,i2,i3,i4,i5,i6,i7,w1,w2,w3,w4,w5,w6,w7);
}

template<int LQ>
__device__ __forceinline__ void inv_pair(float2* __restrict__ Sa, float2* __restrict__ Sb, int p) {
    const int q = 1 << LQ;
    const int m = p & (q - 1);
    const int B = ((p >> LQ) << (LQ + 3)) + m;
    const int i0=PADL(B),i1=PADL(B+q),i2=PADL(B+2*q),i3=PADL(B+3*q),
              i4=PADL(B+4*q),i5=PADL(B+5*q),i6=PADL(B+6*q),i7=PADL(B+7*q);
    float sn, cs;
    __sincosf(TWO_PI * (float)m / (float)(q << 3), &sn, &cs);
    float2 w1 = make_float2(cs, sn);
    WCHAIN(w1, w2,w3,w4,w5,w6,w7);
    inv_one(Sa,i0,i1,i2,i3,i4,i5,i6,i7,w1,w2,w3,w4,w5,w6,w7);
    inv_one(Sb,i0,i1,i2,i3,i4,i5,i6,i7,w1,w2,w3,w4,w5,w6,w7);
}

template<int LQ>
__device__ __forceinline__ void fwd_single(float2* __restrict__ S, int p) {
    const int q = 1 << LQ;
    const int m = p & (q - 1);
    const int B = ((p >> LQ) << (LQ + 3)) + m;
    const int i0=PADL(B),i1=PADL(B+q),i2=PADL(B+2*q),i3=PADL(B+3*q),
              i4=PADL(B+4*q),i5=PADL(B+5*q),i6=PADL(B+6*q),i7=PADL(B+7*q);
    float sn, cs;
    __sincosf(-TWO_PI * (float)m / (float)(q << 3), &sn, &cs);
    float2 w1 = make_float2(cs, sn);
    WCHAIN(w1, w2,w3,w4,w5,w6,w7);
    fwd_one(S,i0,i1,i2,i3,i4,i5,i6,i7,w1,w2,w3,w4,w5,w6,w7);
}

// Q' = Xd*Td + i*Xe*Te  (Td,Te pre-scaled by 0.5/8192 in tsep)
__device__ __forceinline__ float2 qmul(float2 a, float2 A, float4 t) {
    float2 Xd = make_float2((a.x + A.x) * 0.5f, (a.y - A.y) * 0.5f);
    float2 Xe = make_float2((a.y + A.y) * 0.5f, (A.x - a.x) * 0.5f);
    float2 A0 = cmul(Xd, make_float2(t.x, t.y));
    float2 B0 = cmul(Xe, make_float2(t.z, t.w));
    return make_float2(A0.x - B0.y, A0.y + B0.x);
}

// sep on both halves of one pair; one internal barrier
__device__ __forceinline__ void sep_both(float2* __restrict__ Se, float2* __restrict__ So,
                                         const float4* __restrict__ tbE,
                                         const float4* __restrict__ tbO, int p) {
    float2 We[8], Wo[8];
    #pragma unroll
    for (int it = 0; it < 8; ++it) {
        int u = p + (it << 9);
        int K = rev8_12(u);
        int vE = rev8_12((4096 - K) & 4095);       // even half: partner m' = (4096-m)%4096
        int vO = rev8_12(4095 - K);                // odd  half: partner m' = 4095-m
        float2 ae = Se[PADL(u)], Ae = Se[PADL(vE)];
        We[it] = qmul(ae, Ae, tbE[u]);
        float2 ao = So[PADL(u)], Ao = So[PADL(vO)];
        Wo[it] = qmul(ao, Ao, tbO[u]);
    }
    __syncthreads();
    #pragma unroll
    for (int it = 0; it < 8; ++it) {
        int u = p + (it << 9);
        Se[PADL(u)] = We[it];
        So[PADL(u)] = Wo[it];
    }
}

// ---------------- T precompute: 256 blocks x 1024 thr ----------------
__global__ __launch_bounds__(1024, 2) void tsep_k(
    const float* __restrict__ T, float4* __restrict__ Tsep)
{
    extern __shared__ float2 L[];
    float2* Te = L;
    float2* To = L + BUF_ELEMS;
    const int tid = threadIdx.x;

    int h = blockIdx.x;                        // [0,256)
    const int c = ((h & 7) << 5) | (h >> 3);   // 32 consecutive pairs per XCD
    const float* tp = T + (c << 1);

    // fold + modulate: Te[r] = t[r]+t[r+4096]; To[r] = (t[r]-t[r+4096])*e^{-2pi i r/8192}
    {
        float sn, cs;
        __sincosf(-TWO_PI * (float)tid / 8192.0f, &sn, &cs);
        float2 m = make_float2(cs, sn);
        const float2 CF4 = make_float2(RSQRT2, -RSQRT2);   // e^{-i pi/4} per 1024-step
        #pragma unroll
        for (int j = 0; j < 4; ++j) {
            int r = tid + (j << 10);
            float2 va = *(const float2*)(tp + (size_t)r * 512);
            float2 vb = *(const float2*)(tp + (size_t)(r + 4096) * 512);
            Te[PADL(r)] = cadd(va, vb);
            To[PADL(r)] = cmul(csub(va, vb), m);
            m = cmul(m, CF4);
        }
    }
    __syncthreads();                                           // B1

    const int p = tid & 511;
    float2* Sb = (tid >> 9) ? To : Te;
    fwd_single<9>(Sb, p);
    __syncthreads();                                           // B2
    fwd_single<6>(Sb, p);  WFENCE();
    fwd_single<3>(Sb, p);  WFENCE();
    plain_one_fwd(Sb, p);
    __syncthreads();                                           // B3

    const float sc = 0.5f / 8192.0f;
    const int parity = tid >> 9;
    float4* tb = Tsep + (size_t)c * 8192 + (parity << 12);
    #pragma unroll
    for (int it = 0; it < 8; ++it) {
        int u = p + (it << 9);
        int K = rev8_12(u);
        int v = parity ? rev8_12(4095 - K) : rev8_12((4096 - K) & 4095);
        float2 Zk = Sb[PADL(u)], Zn = Sb[PADL(v)];
        tb[u] = make_float4((Zk.x + Zn.x) * sc, (Zk.y - Zn.y) * sc,
                            (Zk.y + Zn.y) * sc, (Zn.x - Zk.x) * sc);
    }
}

// ---------------- main conv: 512 blocks x 1024 thr ----------------
__global__ __launch_bounds__(1024, 2) void fftconv10(
    const float* __restrict__ X, const float4* __restrict__ Tsep,
    float* __restrict__ O)
{
    extern __shared__ float2 L[];
    const int tid = threadIdx.x;

    // R5 swizzle: 4 consecutive-g blocks per XCD
    int h = blockIdx.x;                        // [0,512)
    int xcd = h & 7, sl = h >> 3;
    int lbid = ((sl >> 2) << 5) | (xcd << 2) | (sl & 3);
    const int b = lbid >> 7;
    const int g = lbid & 127;                  // 2 pairs = 4 channels
    const float* xp = X + (size_t)b * 4096 * 512 + (g << 2);

    float2* Ze0 = L;
    float2* Zo0 = L + BUF_ELEMS;
    float2* Ze1 = L + 2 * BUF_ELEMS;
    float2* Zo1 = L + 3 * BUF_ELEMS;

    // ---- load float4 rows; raw -> Ze, modulated -> Zo ----
    {
        float sn, cs;
        __sincosf(-TWO_PI * (float)tid / 8192.0f, &sn, &cs);
        float2 m = make_float2(cs, sn);
        const float2 CF4 = make_float2(RSQRT2, -RSQRT2);   // e^{-i pi/4}
        #pragma unroll
        for (int j = 0; j < 4; ++j) {
            int r = tid + (j << 10);
            float4 v = *(const float4*)(xp + (size_t)r * 512);
            float2 z0 = make_float2(v.x, v.y);
            float2 z1 = make_float2(v.z, v.w);
            Ze0[PADL(r)] = z0;
            Zo0[PADL(r)] = cmul(z0, m);
            Ze1[PADL(r)] = z1;
            Zo1[PADL(r)] = cmul(z1, m);
            m = cmul(m, CF4);
        }
    }
    __syncthreads();                                           // B1

    const int p = tid & 511;
    const int bp = tid >> 9;                   // which pair this thread owns
    float2* Sa = L + (size_t)(2 * bp) * BUF_ELEMS;     // Ze of my pair
    float2* Sb = Sa + BUF_ELEMS;                        // Zo of my pair

    fwd_pair<9>(Sa, Sb, p);
    __syncthreads();                                           // B2
    fwd_pair<6>(Sa, Sb, p);  WFENCE();                         // wave-local
    fwd_pair<3>(Sa, Sb, p);  WFENCE();                         // wave-local
    plain_one_fwd(Sa, p);    plain_one_fwd(Sb, p);
    __syncthreads();                                           // B3

    const int cglob = 2 * g + bp;
    const float4* tbE = Tsep + (size_t)cglob * 8192;
    sep_both(Sa, Sb, tbE, tbE + 4096, p);                      // internal B4
    __syncthreads();                                           // B5

    plain_one_inv(Sa, p);    plain_one_inv(Sb, p);  WFENCE();  // wave-local
    inv_pair<3>(Sa, Sb, p);  WFENCE();                         // wave-local
    inv_pair<6>(Sa, Sb, p);
    __syncthreads();                                           // B6

    // ---- inverse final (q=512) + even/odd recombine + store ----
    {
        float sn, cs;
        __sincosf(TWO_PI * (float)p / 4096.0f, &sn, &cs);
        float2 w1 = make_float2(cs, sn);
        WCHAIN(w1, w2,w3,w4,w5,w6,w7);
        float2 e0 = Sa[PADL(p)];
        float2 e1 = cmul(Sa[PADL(p +  512)], w1);
        float2 e2 = cmul(Sa[PADL(p + 1024)], w2);
        float2 e3 = cmul(Sa[PADL(p + 1536)], w3);
        float2 e4 = cmul(Sa[PADL(p + 2048)], w4);
        float2 e5 = cmul(Sa[PADL(p + 2560)], w5);
        float2 e6 = cmul(Sa[PADL(p + 3072)], w6);
        float2 e7 = cmul(Sa[PADL(p + 3584)], w7);
        dft8_inv(e0,e1,e2,e3,e4,e5,e6,e7);
        float2 o0 = Sb[PADL(p)];
        float2 o1 = cmul(Sb[PADL(p +  512)], w1);
        float2 o2 = cmul(Sb[PADL(p + 1024)], w2);
        float2 o3 = cmul(Sb[PADL(p + 1536)], w3);
        float2 o4 = cmul(Sb[PADL(p + 2048)], w4);
        float2 o5 = cmul(Sb[PADL(p + 2560)], w5);
        float2 o6 = cmul(Sb[PADL(p + 3072)], w6);
        float2 o7 = cmul(Sb[PADL(p + 3584)], w7);
        dft8_inv(o0,o1,o2,o3,o4,o5,o6,o7);

        __sincosf(TWO_PI * (float)p / 8192.0f, &sn, &cs);
        float2 cmb = make_float2(cs, sn);                      // e^{+2pi i p/8192}
        const float2 CI8 = make_float2(0.92387953251128675613f,
                                       0.38268343236508977173f); // e^{+i pi/8}
        float* op = O + (size_t)b * 4096 * 512 + (g << 2) + (bp << 1);
        *(float2*)(op + (size_t)(p         ) * 512) = cadd(e0, cmul(o0, cmb)); cmb = cmul(cmb, CI8);
        *(float2*)(op + (size_t)(p +  512) * 512) = cadd(e1, cmul(o1, cmb)); cmb = cmul(cmb, CI8);
        *(float2*)(op + (size_t)(p + 1024) * 512) = cadd(e2, cmul(o2, cmb)); cmb = cmul(cmb, CI8);
        *(float2*)(op + (size_t)(p + 1536) * 512) = cadd(e3, cmul(o3, cmb)); cmb = cmul(cmb, CI8);
        *(float2*)(op + (size_t)(p + 2048) * 512) = cadd(e4, cmul(o4, cmb)); cmb = cmul(cmb, CI8);
        *(float2*)(op + (size_t)(p + 2560) * 512) = cadd(e5, cmul(o5, cmb)); cmb = cmul(cmb, CI8);
        *(float2*)(op + (size_t)(p + 3072) * 512) = cadd(e6, cmul(o6, cmb)); cmb = cmul(cmb, CI8);
        *(float2*)(op + (size_t)(p + 3584) * 512) = cadd(e7, cmul(o7, cmb));
    }
}

extern "C" void kernel_launch(void* const* d_in, const int* in_sizes, int n_in,
                              void* d_out, int out_size, void* d_ws, size_t ws_size,
                              hipStream_t stream)
{
    const float* x = (const float*)d_in[0];   // (4, 4096, 512)
    const float* t = (const float*)d_in[1];   // (8192, 512)
    float* out = (float*)d_out;               // (4, 4096, 512)
    float4* tsep = (float4*)d_ws;             // 256 pairs * 8192 * 16 B = 32 MB

    const int lds_t = (int)(2 * BUF_ELEMS * sizeof(float2));  // 69632
    const int lds_c = (int)(4 * BUF_ELEMS * sizeof(float2));  // 139264
    (void)hipFuncSetAttribute((const void*)tsep_k,
                              hipFuncAttributeMaxDynamicSharedMemorySize, lds_t);
    (void)hipFuncSetAttribute((const void*)fftconv10,
                              hipFuncAttributeMaxDynamicSharedMemorySize, lds_c);

    tsep_k<<<256, 1024, lds_t, stream>>>(t, tsep);
    fftconv10<<<512, 1024, lds_c, stream>>>(x, tsep, out);
}